// Round 8
// baseline (189.552 us; speedup 1.0000x reference)
//
#include <hip/hip_runtime.h>

typedef __bf16 bf16x8 __attribute__((ext_vector_type(8)));
typedef float f32x4 __attribute__((ext_vector_type(4)));

#define DEV __device__ __forceinline__

DEV unsigned short f2bf(float f) {
  union { float f; unsigned u; } x; x.f = f;
  unsigned r = x.u + 0x7FFFu + ((x.u >> 16) & 1u);  // RNE
  return (unsigned short)(r >> 16);
}
DEV float bf2f(unsigned short h) {
  union { unsigned u; float f; } x; x.u = ((unsigned)h) << 16;
  return x.f;
}

typedef __attribute__((address_space(3))) void* lds_vp;
typedef const __attribute__((address_space(1))) void* gbl_vp;
DEV void load_lds16(const unsigned short* gp, void* lp) {
  __builtin_amdgcn_global_load_lds((gbl_vp)(const void*)gp, (lds_vp)lp, 16, 0, 0);
}

// ---- fused ingest (inputs f32): convert x/rel/bo, transpose Wq|Wkv|Wo -----
__global__ __launch_bounds__(256)
void prep_k(const float* __restrict__ x, const float* __restrict__ rel,
            const float* __restrict__ bo, const float* __restrict__ Wq,
            const float* __restrict__ Wkv, const float* __restrict__ Wo,
            unsigned short* __restrict__ xb, unsigned short* __restrict__ relb,
            unsigned short* __restrict__ bob, unsigned short* __restrict__ WqkvT,
            unsigned short* __restrict__ WoT) {
  __shared__ unsigned short tile[32][33];
  const int bid = blockIdx.x, tid = threadIdx.x;
  if (bid < 2114) {
    const float* src; unsigned short* dst; long base; long n;
    if (bid < 2048)      { src = x;   dst = xb;   base = (long)bid * 1024;          n = 2097152; }
    else if (bid < 2113) { src = rel; dst = relb; base = (long)(bid - 2048) * 1024; n = 65600; }
    else                 { src = bo;  dst = bob;  base = 0;                          n = 1024; }
    long i = base + tid * 4;
    if (i < n) {
      float4 v = *(const float4*)&src[i];
      unsigned long long u = (unsigned long long)f2bf(v.x)
                           | ((unsigned long long)f2bf(v.y) << 16)
                           | ((unsigned long long)f2bf(v.z) << 32)
                           | ((unsigned long long)f2bf(v.w) << 48);
      *(unsigned long long*)&dst[i] = u;
    }
  } else {
    int id = bid - 2114;
    const float* src; unsigned short* dst; const int R = 1024; int C, txt, tyt;
    if (id < 1024)      { src = Wq;  dst = WqkvT;           C = 1024; txt = id & 31; tyt = id >> 5; }
    else if (id < 3072) { int l = id - 1024; src = Wkv; dst = WqkvT + 1048576; C = 2048; txt = l & 63; tyt = l >> 6; }
    else                { int l = id - 3072; src = Wo;  dst = WoT;             C = 1024; txt = l & 31; tyt = l >> 5; }
    int c0 = txt * 32, r0 = tyt * 32;
    int tx = tid & 31, ty = tid >> 5;
    #pragma unroll
    for (int i = 0; i < 4; ++i)
      tile[ty + i * 8][tx] = f2bf(src[(size_t)(r0 + ty + i * 8) * C + c0 + tx]);
    __syncthreads();
    #pragma unroll
    for (int i = 0; i < 4; ++i)
      dst[(size_t)(c0 + ty + i * 8) * R + r0 + tx] = tile[tx][ty + i * 8];
  }
}

// ---------------- GEMM qkv = x @ WqkvT^T; q*0.125; all [b,h,n,d] coalesced --
__global__ __launch_bounds__(256)
void gemm_qkv(const unsigned short* __restrict__ A,
              const unsigned short* __restrict__ Bt,
              unsigned short* __restrict__ o0,   // q
              unsigned short* __restrict__ o1,   // k
              unsigned short* __restrict__ o2) { // v row-major
  __shared__ __align__(16) unsigned short As[128][32];
  __shared__ __align__(16) unsigned short Bs[128][32];
  const int tid  = threadIdx.x;
  const int lane = tid & 63, wave = tid >> 6;
  const int q15  = lane & 15, quad = lane >> 4;
  const int wr = wave >> 1, wc = wave & 1;
  const int m0 = blockIdx.y * 128, n0 = blockIdx.x * 128;
  const int K = 1024;
  const int lrow = lane >> 2, lkc = (lane & 3) * 8;

  f32x4 acc[4][4] = {};
  for (int k0 = 0; k0 < K; k0 += 32) {
    __syncthreads();
    #pragma unroll
    for (int t = 0; t < 2; ++t) {
      int r0 = wave * 32 + t * 16;
      load_lds16(&A[(size_t)(m0 + r0 + lrow) * K + k0 + lkc], &As[r0][0]);
      load_lds16(&Bt[(size_t)(n0 + r0 + lrow) * K + k0 + lkc], &Bs[r0][0]);
    }
    __syncthreads();
    bf16x8 af[4], bfr[4];
    #pragma unroll
    for (int i = 0; i < 4; ++i) {
      af[i]  = *(const bf16x8*)&As[wr * 64 + i * 16 + q15][quad * 8];
      bfr[i] = *(const bf16x8*)&Bs[wc * 64 + i * 16 + q15][quad * 8];
    }
    #pragma unroll
    for (int i = 0; i < 4; ++i)
      #pragma unroll
      for (int j = 0; j < 4; ++j)
        acc[i][j] = __builtin_amdgcn_mfma_f32_16x16x32_bf16(af[i], bfr[j], acc[i][j], 0, 0, 0);
  }
  #pragma unroll
  for (int i = 0; i < 4; ++i)
    #pragma unroll
    for (int j = 0; j < 4; ++j)
      #pragma unroll
      for (int r = 0; r < 4; ++r) {
        int row = m0 + wr * 64 + i * 16 + quad * 4 + r;
        int col = n0 + wc * 64 + j * 16 + q15;
        float v = acc[i][j][r];
        int b = row >> 10, nn = row & 1023;
        unsigned short* dst; int c = col; float sc = 1.f;
        if (col < 1024)      { dst = o0; sc = 0.125f; }
        else if (col < 2048) { dst = o1; c = col - 1024; }
        else                 { dst = o2; c = col - 2048; }
        int h = c >> 6, dd = c & 63;
        dst[((size_t)(b * 16 + h) * 1024 + nn) * 64 + dd] = f2bf(v * sc);
      }
}

// ---- per-head V transpose: v[bh][n][d] -> vT[bh][d][n]
__global__ __launch_bounds__(256)
void transpose_v_k(const unsigned short* __restrict__ v,
                   unsigned short* __restrict__ vt) {
  __shared__ __align__(16) unsigned short st[64][68];
  const int bh = blockIdx.y, n0 = blockIdx.x * 64;
  const unsigned short* vp = v + (size_t)bh * 1024 * 64;
  unsigned short* tp = vt + (size_t)bh * 64 * 1024;
  #pragma unroll
  for (int cc = 0; cc < 2; ++cc) {
    int ci = threadIdx.x + cc * 256;
    int row = ci >> 3, dc = (ci & 7) * 8;
    *(uint4*)&st[row][dc] = *(const uint4*)&vp[(size_t)(n0 + row) * 64 + dc];
  }
  __syncthreads();
  #pragma unroll
  for (int cc = 0; cc < 2; ++cc) {
    int ci = threadIdx.x + cc * 256;
    int d = ci >> 3, nc = (ci & 7) * 8;
    union { uint4 v; unsigned short us[8]; } t;
    #pragma unroll
    for (int e = 0; e < 8; ++e) t.us[e] = st[nc + e][d];
    *(uint4*)&tp[(size_t)d * 1024 + n0 + nc] = t.v;
  }
}

// ---- swizzled tile staging: [64 rows][64 shorts], chunk ^= row&7 ----------
DEV void stage16(const unsigned short* gbase, size_t gstride,
                 unsigned short* lbase, int r0, int lane) {
  #pragma unroll
  for (int t = 0; t < 2; ++t) {
    int r = r0 + t * 8 + (lane >> 3);
    int lc = (lane & 7) ^ (r & 7);
    load_lds16(&gbase[(size_t)r * gstride + lc * 8], &lbase[(size_t)(r0 + t * 8) * 64]);
  }
}
DEV bf16x8 read_swz(const unsigned short* buf, int row, int lc) {
  int pc = lc ^ (row & 7);
  return *(const bf16x8*)&buf[row * 64 + pc * 8];
}

// ---------------- flash attention: split-j, dbuf staging, shuffle-T --------
// grid (x=bh 32 -> XCD locality, y = i-tile*2 + split); 8 j-tiles of 64 each.
// 1 barrier/jt: prefetch tile jt+1 into buf[1-cur] overlaps compute of jt.
// LDS = 16K(K) + 16K(V) + 8K(P swizzled) = 40 KB -> 4 blocks/CU.
__global__ __launch_bounds__(256)
void flash_attn(const unsigned short* __restrict__ q_ws,   // pre-scaled .125
                const unsigned short* __restrict__ k_ws,
                const unsigned short* __restrict__ vt_ws,  // [bh][64][1024]
                const unsigned short* __restrict__ rel,    // [1025][64]
                unsigned short* __restrict__ Opart,        // [2][32][1024][64]
                float* __restrict__ lpart) {               // [2][32*1024]
  __shared__ __align__(16) unsigned short Kbuf[2][64 * 64];
  __shared__ __align__(16) unsigned short Vbuf[2][64 * 64];
  __shared__ __align__(16) unsigned short P_lds[4][16 * 64];  // XOR-8 swizzled

  const int tid  = threadIdx.x;
  const int lane = tid & 63, w = tid >> 6;
  const int q15  = lane & 15, quad = lane >> 4;
  const int bh = blockIdx.x;
  const int it = blockIdx.y >> 1, sp = blockIdx.y & 1;
  const int ib = it * 64 + w * 16;
  const int jbase = sp * 512;

  const unsigned short* qp = q_ws  + (size_t)bh * 1024 * 64;
  const unsigned short* kp = k_ws  + (size_t)bh * 1024 * 64;
  const unsigned short* tp = vt_ws + (size_t)bh * 64 * 1024;

  bf16x8 aq[2];
  #pragma unroll
  for (int ks = 0; ks < 2; ++ks)
    aq[ks] = *(const bf16x8*)&qp[(size_t)(ib + q15) * 64 + ks * 32 + quad * 8];

  f32x4 o[4] = {};
  float l_i[4] = {0.f, 0.f, 0.f, 0.f};

  // prologue: stage tile 0
  stage16(kp + (size_t)jbase * 64, 64, &Kbuf[0][0], w * 16, lane);
  stage16(tp + jbase, 1024, &Vbuf[0][0], w * 16, lane);

  for (int jt = 0; jt < 8; ++jt) {
    const int j0 = jbase + jt * 64, cur = jt & 1;
    __syncthreads();  // buf[cur] staged by all waves; buf[cur^1] free to fill
    if (jt + 1 < 8) {
      stage16(kp + (size_t)(j0 + 64) * 64, 64, &Kbuf[cur ^ 1][0], w * 16, lane);
      stage16(tp + (j0 + 64), 1024, &Vbuf[cur ^ 1][0], w * 16, lane);
    }

    // Q K^T
    f32x4 accS[4] = {};
    #pragma unroll
    for (int ks = 0; ks < 2; ++ks)
      #pragma unroll
      for (int cb = 0; cb < 4; ++cb) {
        bf16x8 bk = read_swz(&Kbuf[cur][0], cb * 16 + q15, ks * 4 + quad);
        accS[cb] = __builtin_amdgcn_mfma_f32_16x16x32_bf16(aq[ks], bk, accS[cb], 0, 0, 0);
      }
    // positional band T[16][80] in MFMA C-layout registers
    int tb = ib - j0 + 512 - 63;
    f32x4 accT[5] = {};
    #pragma unroll
    for (int ks = 0; ks < 2; ++ks)
      #pragma unroll
      for (int ub = 0; ub < 5; ++ub) {
        int trow = tb + ub * 16 + q15;
        trow = trow < 0 ? 0 : (trow > 1024 ? 1024 : trow);
        bf16x8 br = *(const bf16x8*)&rel[(size_t)trow * 64 + ks * 32 + quad * 8];
        accT[ub] = __builtin_amdgcn_mfma_f32_16x16x32_bf16(aq[ks], br, accT[ub], 0, 0, 0);
      }

    // softmax numerators: gather T via quad-group shuffles, exp, stage P
    #pragma unroll
    for (int r = 0; r < 4; ++r) {
      const int dl = quad * 4 + r;
      const int src = quad * 16 + ((15 + dl - q15) & 15);
      float tv[5];
      #pragma unroll
      for (int ub = 0; ub < 5; ++ub)
        tv[ub] = __shfl(accT[ub][r], src, 64);
      const bool hi = (q15 < dl);  // (63+dl-q15) >= 64
      #pragma unroll
      for (int cb = 0; cb < 4; ++cb) {
        float tval = hi ? tv[4 - cb] : tv[3 - cb];
        float s = accS[cb][r] + tval;
        float p = exp2f(s * 1.44269504f - 64.f);
        l_i[r] += p;
        int k = cb * 16 + q15;
        P_lds[w][dl * 64 + ((((k >> 3) ^ (dl & 7)) << 3) | (k & 7))] = f2bf(p);
      }
    }

    // O += P @ V (P per-wave swizzled LDS; V^T swizzled)
    #pragma unroll
    for (int ks = 0; ks < 2; ++ks) {
      bf16x8 ap = *(const bf16x8*)&P_lds[w][q15 * 64 + (((ks * 4 + quad) ^ (q15 & 7)) << 3)];
      #pragma unroll
      for (int db = 0; db < 4; ++db) {
        bf16x8 bv = read_swz(&Vbuf[cur][0], db * 16 + q15, ks * 4 + quad);
        o[db] = __builtin_amdgcn_mfma_f32_16x16x32_bf16(ap, bv, o[db], 0, 0, 0);
      }
    }
  }

  // l: reduce across the 16 lanes of each quad group
  #pragma unroll
  for (int r = 0; r < 4; ++r)
    #pragma unroll
    for (int off = 1; off < 16; off <<= 1)
      l_i[r] += __shfl_xor(l_i[r], off, 64);

  unsigned short* op = Opart + ((size_t)sp * 32 + bh) * 1024 * 64;
  #pragma unroll
  for (int db = 0; db < 4; ++db)
    #pragma unroll
    for (int r = 0; r < 4; ++r) {
      int row = ib + quad * 4 + r;
      op[(size_t)row * 64 + db * 16 + q15] = f2bf(o[db][r]);
    }
  if (q15 == 0)
    #pragma unroll
    for (int r = 0; r < 4; ++r)
      lpart[(size_t)sp * 32768 + bh * 1024 + ib + quad * 4 + r] = l_i[r];
}

// ---- combine partials -> ao[b*1024+i][h*64+d] bf16 ------------------------
__global__ __launch_bounds__(256)
void combine_k(const unsigned short* __restrict__ Opart,
               const float* __restrict__ lpart,
               unsigned short* __restrict__ ao) {
  int e = (blockIdx.x * 256 + threadIdx.x) * 4;  // 2M elements, 4 per thread
  if (e >= 2097152) return;
  int bh = e >> 16, rem = e & 65535, row = rem >> 6, d = e & 63;
  size_t off = (size_t)bh * 65536 + rem;
  const unsigned short* p0 = Opart + off;
  const unsigned short* p1 = Opart + 2097152 + off;
  float li = 1.f / (lpart[bh * 1024 + row] + lpart[32768 + bh * 1024 + row] + 1e-30f);
  ushort2 a0 = *(const ushort2*)p0, a1 = *(const ushort2*)(p0 + 2);
  ushort2 b0 = *(const ushort2*)p1, b1 = *(const ushort2*)(p1 + 2);
  int b = bh >> 4, h = bh & 15;
  unsigned short* dst = ao + ((size_t)(b * 1024 + row)) * 1024 + h * 64 + d;
  dst[0] = f2bf((bf2f(a0.x) + bf2f(b0.x)) * li);
  dst[1] = f2bf((bf2f(a0.y) + bf2f(b0.y)) * li);
  dst[2] = f2bf((bf2f(a1.x) + bf2f(b1.x)) * li);
  dst[3] = f2bf((bf2f(a1.y) + bf2f(b1.y)) * li);
}

// ---------------- GEMM out = ao @ WoT^T + bo (f32 out), 128x64 tiles -------
__global__ __launch_bounds__(256)
void gemm_out(const unsigned short* __restrict__ A,
              const unsigned short* __restrict__ Bt,
              const unsigned short* __restrict__ bias,
              float* __restrict__ fo) {
  __shared__ __align__(16) unsigned short As[128][32];
  __shared__ __align__(16) unsigned short Bs[64][32];
  const int tid  = threadIdx.x;
  const int lane = tid & 63, w = tid >> 6;
  const int q15  = lane & 15, quad = lane >> 4;
  const int m0 = blockIdx.y * 128, n0 = blockIdx.x * 64;
  const int K = 1024, N = 1024;
  const int lrow = lane >> 2, lkc = (lane & 3) * 8;

  f32x4 acc[2][4] = {};
  for (int k0 = 0; k0 < K; k0 += 32) {
    __syncthreads();
    #pragma unroll
    for (int t = 0; t < 2; ++t) {
      int r0 = w * 32 + t * 16;
      load_lds16(&A[(size_t)(m0 + r0 + lrow) * K + k0 + lkc], &As[r0][0]);
    }
    load_lds16(&Bt[(size_t)(n0 + w * 16 + lrow) * K + k0 + lkc], &Bs[w * 16][0]);
    __syncthreads();
    bf16x8 af[2], bfr[4];
    #pragma unroll
    for (int i = 0; i < 2; ++i)
      af[i] = *(const bf16x8*)&As[w * 32 + i * 16 + q15][quad * 8];
    #pragma unroll
    for (int j = 0; j < 4; ++j)
      bfr[j] = *(const bf16x8*)&Bs[j * 16 + q15][quad * 8];
    #pragma unroll
    for (int i = 0; i < 2; ++i)
      #pragma unroll
      for (int j = 0; j < 4; ++j)
        acc[i][j] = __builtin_amdgcn_mfma_f32_16x16x32_bf16(af[i], bfr[j], acc[i][j], 0, 0, 0);
  }
  #pragma unroll
  for (int i = 0; i < 2; ++i)
    #pragma unroll
    for (int j = 0; j < 4; ++j)
      #pragma unroll
      for (int r = 0; r < 4; ++r) {
        int row = m0 + w * 32 + i * 16 + quad * 4 + r;
        int col = n0 + j * 16 + q15;
        fo[(size_t)row * N + col] = acc[i][j][r] + bf2f(bias[col]);
      }
}

// ---------------------------------------------------------------------------
extern "C" void kernel_launch(void* const* d_in, const int* in_sizes, int n_in,
                              void* d_out, int out_size, void* d_ws, size_t ws_size,
                              hipStream_t stream) {
  (void)in_sizes; (void)n_in; (void)out_size; (void)ws_size;
  const float* x   = (const float*)d_in[0];
  const float* Wq  = (const float*)d_in[1];
  const float* Wkv = (const float*)d_in[2];
  const float* Wo  = (const float*)d_in[3];
  const float* bo  = (const float*)d_in[4];
  const float* rel = (const float*)d_in[5];
  float* out = (float*)d_out;

  unsigned short* ws = (unsigned short*)d_ws;
  unsigned short* WoT   = ws;                      // 1,048,576
  unsigned short* relb  = WoT   + 1048576;         // 65,664 reserved
  unsigned short* bob   = relb  + 65664;           // 1,088 reserved
  unsigned short* q_ws  = bob   + 1088;            // 2,097,152
  unsigned short* k_ws  = q_ws  + 2097152;         // 2,097,152
  unsigned short* vT    = k_ws  + 2097152;         // 2,097,152
  unsigned short* WqkvT = vT    + 2097152;         // 3,145,728 (dead after gemm1)
  unsigned short* xb    = WqkvT + 3145728;         // 2,097,152 (dead after gemm1)
  unsigned short* v_row = xb    + 2097152;         // 2,097,152 (dead after trans_v)
  float*          lpart = (float*)(v_row + 2097152); // 65,536 f32
  // aliases:
  unsigned short* Opart = WqkvT;  // 2 x 2,097,152 bf16 over WqkvT+xb
  unsigned short* ao    = v_row;  // combine output over v_row

  prep_k<<<6210, 256, 0, stream>>>(x, rel, bo, Wq, Wkv, Wo,
                                   xb, relb, bob, WqkvT, WoT);
  gemm_qkv<<<dim3(24, 16), 256, 0, stream>>>(xb, WqkvT, q_ws, k_ws, v_row);
  transpose_v_k<<<dim3(16, 32), 256, 0, stream>>>(v_row, vT);
  flash_attn<<<dim3(32, 32), 256, 0, stream>>>(q_ws, k_ws, vT, relb, Opart, lpart);
  combine_k<<<2048, 256, 0, stream>>>(Opart, lpart, ao);
  gemm_out<<<dim3(16, 16), 256, 0, stream>>>(ao, WoT, bob, out);
}